// Round 6
// baseline (376.929 us; speedup 1.0000x reference)
//
#include <hip/hip_runtime.h>
#include <math.h>

#define SEQ    2048
#define DIMM   512
#define SH     128
#define EXP    1024
#define PROJ_  2176
#define NBATCH 8
#define ROWS   16384  // NBATCH*SEQ

#define KER_SCALE     16384.0f
#define KER_SCALE_INV (1.0f / 16384.0f)
#define QK_INV        (1.0f / (4096.0f * 2048.0f))   // q,k scaled x64 each; /MAX_LEN
#define W8            64.0f                          // generic fp8 pre-scale
#define OUT_INV       (1.0f / 4096.0f)               // ob x64, W2 x64

typedef __attribute__((ext_vector_type(8))) short   short8;
typedef __attribute__((ext_vector_type(4))) float   floatx4;

__device__ __forceinline__ unsigned short f2bf(float f) {
  union { float f; unsigned int u; } v; v.f = f;
  unsigned int r = (v.u + 0x7fffu + ((v.u >> 16) & 1u)) >> 16;
  return (unsigned short)r;
}
__device__ __forceinline__ float bf2f(unsigned short h) {
  union { unsigned int u; float f; } v; v.u = ((unsigned int)h) << 16;
  return v.f;
}
__device__ __forceinline__ unsigned char f2fp8(float f) {
  return (unsigned char)(__builtin_amdgcn_cvt_pk_fp8_f32(f, 0.0f, 0, false) & 0xffu);
}
__device__ __forceinline__ float fp82f(unsigned char b) {
  int e = (b >> 3) & 15, m = b & 7;
  float v = ldexpf((float)(e ? (8 + m) : m), (e ? e : 1) - 10);
  return (b & 0x80) ? -v : v;
}

// =================== fused prep (256 threads) ===================
__device__ __forceinline__ void transpose_tile_bf16(const float* __restrict__ in,
                                                    unsigned short* __restrict__ out,
                                                    int R, int C, int bx, int by, float* tile) {
  int tx = threadIdx.x & 31, ty = threadIdx.x >> 5;
  int c0 = bx * 32, r0 = by * 32;
  #pragma unroll
  for (int j = 0; j < 32; j += 8)
    tile[(ty + j) * 33 + tx] = in[(long)(r0 + ty + j) * C + c0 + tx];
  __syncthreads();
  #pragma unroll
  for (int j = 0; j < 32; j += 8)
    out[(long)(c0 + ty + j) * R + r0 + tx] = f2bf(tile[tx * 33 + ty + j]);
}

__device__ __forceinline__ void transpose_tile_fp8(const float* __restrict__ in,
                                                   unsigned char* __restrict__ out,
                                                   int R, int C, int bx, int by, float* tile) {
  int tx = threadIdx.x & 31, ty = threadIdx.x >> 5;
  int c0 = bx * 32, r0 = by * 32;
  #pragma unroll
  for (int j = 0; j < 32; j += 8)
    tile[(ty + j) * 33 + tx] = in[(long)(r0 + ty + j) * C + c0 + tx];
  __syncthreads();
  #pragma unroll
  for (int j = 0; j < 32; j += 8)
    out[(long)(c0 + ty + j) * R + r0 + tx] = f2fp8(tile[tx * 33 + ty + j] * W8);
}

struct __align__(8) US4 { unsigned short a, b, c, d; };

__global__ void prep_kernel(const float* __restrict__ x, const float* __restrict__ ns,
                            unsigned short* __restrict__ xn,
                            const float* __restrict__ W1, unsigned short* __restrict__ w1t,
                            const float* __restrict__ W2, unsigned char* __restrict__ w2q,
                            const float* __restrict__ ra, const float* __restrict__ rb,
                            float* __restrict__ tpl) {
  __shared__ float sh[33 * 32];
  const int b = blockIdx.x, tid = threadIdx.x;
  if (b < 4096) {
    int wave = tid >> 6, lane = tid & 63;
    long row = (long)b * 4 + wave;
    const float4* xr = (const float4*)(x + row * DIMM);
    float4 v0 = xr[lane], v1 = xr[lane + 64];
    float ss = v0.x*v0.x + v0.y*v0.y + v0.z*v0.z + v0.w*v0.w
             + v1.x*v1.x + v1.y*v1.y + v1.z*v1.z + v1.w*v1.w;
    #pragma unroll
    for (int o = 32; o > 0; o >>= 1) ss += __shfl_xor(ss, o);
    float sc = rsqrtf(ss * (1.0f / DIMM) + 1e-6f) * ns[0];
    US4 w0 = { f2bf(v0.x*sc), f2bf(v0.y*sc), f2bf(v0.z*sc), f2bf(v0.w*sc) };
    US4 w1 = { f2bf(v1.x*sc), f2bf(v1.y*sc), f2bf(v1.z*sc), f2bf(v1.w*sc) };
    ((US4*)(xn + row * DIMM))[lane]      = w0;
    ((US4*)(xn + row * DIMM))[lane + 64] = w1;
  } else if (b < 4096 + 4095) {
    const int d = (b - 4096) - 2047;
    float sum = 0.0f;
    for (int k = tid; k < 1024; k += 256) {
      float a1 = ra[k], a2 = ra[k + 1024];
      float b1v = rb[k], b2v = rb[k + 1024];
      float p = a1 * b1v + a2 * b2v;
      float q = a1 * b2v - a2 * b1v;
      float th = powf(10000.0f, -(float)k * (1.0f / 1024.0f));
      float ang = (float)d * th;
      sum += p * cosf(ang) + q * sinf(ang);
    }
    #pragma unroll
    for (int o = 32; o > 0; o >>= 1) sum += __shfl_xor(sum, o);
    int wave = tid >> 6, lane = tid & 63;
    if (lane == 0) sh[wave] = sum;
    __syncthreads();
    if (tid == 0) tpl[b - 4096] = sh[0] + sh[1] + sh[2] + sh[3];
  } else if (b < 9279) {
    int t = b - 8191;
    transpose_tile_bf16(W1, w1t, DIMM, PROJ_, t % 68, t / 68, sh);
  } else {
    int t = b - 9279;
    transpose_tile_fp8(W2, w2q, EXP, DIMM, t % 16, t / 16, sh);
  }
}

// =================== register-pipelined MFMA cores ===================
// Pipeline: barrier -> issue global loads(k+1) to VGPRs -> compute(k) from LDS
//           -> ds_write regs to other buffer. vmcnt wait lands at ds_write,
//           AFTER compute issue -> load flight overlaps MFMA. vmcnt==0 at
//           every barrier (all loads consumed by ds_writes).

// ---- bf16, 128x128 tile, BK=64; LDS 64 KB (2 x (A16K + B16K)) ----
__device__ __forceinline__ void mfma_core_bf16(const unsigned short* __restrict__ A,
                                               const unsigned short* __restrict__ B,
                                               int K, long rowBase, long colBase,
                                               unsigned short* smem, floatx4 acc[4][4]) {
  unsigned short* Abuf[2] = { smem,         smem + 16384 };
  unsigned short* Bbuf[2] = { smem + 8192,  smem + 24576 };
  const int tid  = threadIdx.x;
  const int wave = tid >> 6, lane = tid & 63;
  const int wr = (wave >> 1) * 64, wc = (wave & 1) * 64;
  const int r_l = lane >> 3, c8 = lane & 7;
  const int gg  = (c8 ^ r_l) * 8;        // this lane's global granule (elements)
  const int fm = lane & 15, fq = lane >> 4;

  long gA[4], gB[4]; int lw[4];
  #pragma unroll
  for (int j = 0; j < 4; ++j) {
    int row = j * 32 + wave * 8 + r_l;
    gA[j] = (rowBase + row) * (long)K + gg;
    gB[j] = (colBase + row) * (long)K + gg;
    lw[j] = row * 64 + c8 * 8;
  }

  floatx4 z = {0.0f, 0.0f, 0.0f, 0.0f};
  #pragma unroll
  for (int mi = 0; mi < 4; ++mi)
    #pragma unroll
    for (int ni = 0; ni < 4; ++ni) acc[mi][ni] = z;

  uint4 rA[4], rB[4];
  #pragma unroll
  for (int j = 0; j < 4; ++j) { rA[j] = *(const uint4*)(A + gA[j]); rB[j] = *(const uint4*)(B + gB[j]); }
  #pragma unroll
  for (int j = 0; j < 4; ++j) { *(uint4*)(Abuf[0] + lw[j]) = rA[j]; *(uint4*)(Bbuf[0] + lw[j]) = rB[j]; }

  const int nIter = K >> 6;
  for (int it = 0; it < nIter; ++it) {
    __syncthreads();
    if (it + 1 < nIter) {
      int k0 = (it + 1) << 6;
      #pragma unroll
      for (int j = 0; j < 4; ++j) {
        rA[j] = *(const uint4*)(A + gA[j] + k0);
        rB[j] = *(const uint4*)(B + gB[j] + k0);
      }
    }
    const unsigned short* As = Abuf[it & 1];
    const unsigned short* Bs = Bbuf[it & 1];
    #pragma unroll
    for (int ks = 0; ks < 2; ++ks) {
      short8 af[4], bfr[4];
      #pragma unroll
      for (int mi = 0; mi < 4; ++mi) {
        int row = wr + mi * 16 + fm;
        int gL = (ks * 4 + fq) ^ (row & 7);
        af[mi] = *(const short8*)(As + row * 64 + gL * 8);
      }
      #pragma unroll
      for (int ni = 0; ni < 4; ++ni) {
        int row = wc + ni * 16 + fm;
        int gL = (ks * 4 + fq) ^ (row & 7);
        bfr[ni] = *(const short8*)(Bs + row * 64 + gL * 8);
      }
      #pragma unroll
      for (int mi = 0; mi < 4; ++mi)
        #pragma unroll
        for (int ni = 0; ni < 4; ++ni)
          acc[mi][ni] = __builtin_amdgcn_mfma_f32_16x16x32_bf16(af[mi], bfr[ni], acc[mi][ni], 0, 0, 0);
    }
    if (it + 1 < nIter) {
      unsigned short* Aw = Abuf[(it + 1) & 1];
      unsigned short* Bw = Bbuf[(it + 1) & 1];
      #pragma unroll
      for (int j = 0; j < 4; ++j) { *(uint4*)(Aw + lw[j]) = rA[j]; *(uint4*)(Bw + lw[j]) = rB[j]; }
    }
  }
}

// ---- fp8 e4m3, 128x128 tile, BK=128; LDS 64 KB ----
__device__ __forceinline__ void mfma_core_fp8(const unsigned char* __restrict__ A,
                                              const unsigned char* __restrict__ B,
                                              int K, long rowBase, long colBase,
                                              unsigned char* smem, floatx4 acc[4][4]) {
  unsigned char* Abuf[2] = { smem,          smem + 32768 };
  unsigned char* Bbuf[2] = { smem + 16384,  smem + 49152 };
  const int tid  = threadIdx.x;
  const int wave = tid >> 6, lane = tid & 63;
  const int wr = (wave >> 1) * 64, wc = (wave & 1) * 64;
  const int r_l = lane >> 3, c8 = lane & 7;
  const int gg  = (c8 ^ r_l) * 16;       // byte offset of lane's global granule
  const int fm = lane & 15, fq = lane >> 4;

  long gA[4], gB[4]; int lw[4];
  #pragma unroll
  for (int j = 0; j < 4; ++j) {
    int row = j * 32 + wave * 8 + r_l;
    gA[j] = (rowBase + row) * (long)K + gg;
    gB[j] = (colBase + row) * (long)K + gg;
    lw[j] = row * 128 + c8 * 16;
  }

  floatx4 z = {0.0f, 0.0f, 0.0f, 0.0f};
  #pragma unroll
  for (int mi = 0; mi < 4; ++mi)
    #pragma unroll
    for (int ni = 0; ni < 4; ++ni) acc[mi][ni] = z;

  uint4 rA[4], rB[4];
  #pragma unroll
  for (int j = 0; j < 4; ++j) { rA[j] = *(const uint4*)(A + gA[j]); rB[j] = *(const uint4*)(B + gB[j]); }
  #pragma unroll
  for (int j = 0; j < 4; ++j) { *(uint4*)(Abuf[0] + lw[j]) = rA[j]; *(uint4*)(Bbuf[0] + lw[j]) = rB[j]; }

  const int nIter = K >> 7;
  for (int it = 0; it < nIter; ++it) {
    __syncthreads();
    if (it + 1 < nIter) {
      int k0 = (it + 1) << 7;
      #pragma unroll
      for (int j = 0; j < 4; ++j) {
        rA[j] = *(const uint4*)(A + gA[j] + k0);
        rB[j] = *(const uint4*)(B + gB[j] + k0);
      }
    }
    const unsigned char* As = Abuf[it & 1];
    const unsigned char* Bs = Bbuf[it & 1];
    #pragma unroll
    for (int ks = 0; ks < 4; ++ks) {
      long af[4], bfr[4];
      #pragma unroll
      for (int mi = 0; mi < 4; ++mi) {
        int row = wr + mi * 16 + fm;
        int g = (ks * 2 + (fq >> 1)) ^ (row & 7);
        af[mi] = *(const long*)(As + row * 128 + g * 16 + (fq & 1) * 8);
      }
      #pragma unroll
      for (int ni = 0; ni < 4; ++ni) {
        int row = wc + ni * 16 + fm;
        int g = (ks * 2 + (fq >> 1)) ^ (row & 7);
        bfr[ni] = *(const long*)(Bs + row * 128 + g * 16 + (fq & 1) * 8);
      }
      #pragma unroll
      for (int mi = 0; mi < 4; ++mi)
        #pragma unroll
        for (int ni = 0; ni < 4; ++ni)
          acc[mi][ni] = __builtin_amdgcn_mfma_f32_16x16x32_fp8_fp8(af[mi], bfr[ni], acc[mi][ni], 0, 0, 0);
    }
    if (it + 1 < nIter) {
      unsigned char* Aw = Abuf[(it + 1) & 1];
      unsigned char* Bw = Bbuf[(it + 1) & 1];
      #pragma unroll
      for (int j = 0; j < 4; ++j) { *(uint4*)(Aw + lw[j]) = rA[j]; *(uint4*)(Bw + lw[j]) = rB[j]; }
    }
  }
}

#define EPILOGUE_VARS                                         \
  const int lane = threadIdx.x & 63, wave = threadIdx.x >> 6; \
  const int wr = (wave >> 1) * 64, wc = (wave & 1) * 64;      \
  const int fr = (lane >> 4) * 4, fc = lane & 15;

// ------------- GEMM1: uv = swish(xn @ W1 + b1); split into u(fp8 x64), vT(fp8), q/k(fp8 x64) -------------
__global__ void __launch_bounds__(256)
gemm_uv(const unsigned short* __restrict__ xn,
        const unsigned short* __restrict__ w1t,
        const float* __restrict__ b1,
        const float* __restrict__ gamma,
        const float* __restrict__ beta,
        unsigned char* __restrict__ uq,
        unsigned char* __restrict__ vT,
        unsigned char* __restrict__ qq,
        unsigned char* __restrict__ kq) {
  __shared__ __align__(16) unsigned short smem[32768];  // 64 KB
  floatx4 acc[4][4];
  long rowBase = (long)blockIdx.x * 128;
  long colBase = (long)blockIdx.y * 128;
  mfma_core_bf16(xn, w1t, DIMM, rowBase, colBase, smem, acc);
  EPILOGUE_VARS

  if (blockIdx.y < 8) {
    #pragma unroll
    for (int mi = 0; mi < 4; ++mi)
    #pragma unroll
    for (int ni = 0; ni < 4; ++ni)
    #pragma unroll
    for (int i = 0; i < 4; ++i) {
      long row = rowBase + wr + mi * 16 + fr + i;
      long col = colBase + wc + ni * 16 + fc;
      float t = acc[mi][ni][i] + b1[col];
      uq[row * EXP + col] = f2fp8(t / (1.0f + __expf(-t)) * W8);
    }
  } else if (blockIdx.y < 16) {
    // v region: LDS transpose -> coalesced fp8 stores into vT
    __syncthreads();
    #pragma unroll
    for (int mi = 0; mi < 4; ++mi)
    #pragma unroll
    for (int ni = 0; ni < 4; ++ni)
    #pragma unroll
    for (int i = 0; i < 4; ++i) {
      int rl = wr + mi * 16 + fr + i;     // n-local
      int cl = wc + ni * 16 + fc;         // e-local
      long col = colBase + cl;
      float t = acc[mi][ni][i] + b1[col];
      smem[cl * 136 + rl] = f2bf(t / (1.0f + __expf(-t)));
    }
    __syncthreads();
    long b_   = rowBase >> 11;
    long nblk = rowBase & 2047;
    long e0   = colBase - EXP;
    #pragma unroll
    for (int rep = 0; rep < 8; ++rep) {
      int cl = rep * 16 + (threadIdx.x >> 4);
      int n0 = (threadIdx.x & 15) * 8;
      const unsigned short* src = smem + cl * 136 + n0;
      unsigned int w0 = __builtin_amdgcn_cvt_pk_fp8_f32(bf2f(src[0]), bf2f(src[1]), 0, false);
      w0 = __builtin_amdgcn_cvt_pk_fp8_f32(bf2f(src[2]), bf2f(src[3]), w0, true);
      unsigned int w1 = __builtin_amdgcn_cvt_pk_fp8_f32(bf2f(src[4]), bf2f(src[5]), 0, false);
      w1 = __builtin_amdgcn_cvt_pk_fp8_f32(bf2f(src[6]), bf2f(src[7]), w1, true);
      uint2 pk; pk.x = w0; pk.y = w1;
      *(uint2*)(vT + (b_ * EXP + e0 + cl) * (long)SEQ + nblk + n0) = pk;
    }
  } else {
    #pragma unroll
    for (int mi = 0; mi < 4; ++mi)
    #pragma unroll
    for (int ni = 0; ni < 4; ++ni)
    #pragma unroll
    for (int i = 0; i < 4; ++i) {
      long row = rowBase + wr + mi * 16 + fr + i;
      long col = colBase + wc + ni * 16 + fc;
      float t = acc[mi][ni][i] + b1[col];
      float s = t / (1.0f + __expf(-t));
      int dd = (int)(col - 2 * EXP);
      qq[row * SH + dd] = f2fp8((s * gamma[dd] + beta[dd]) * W8);
      kq[row * SH + dd] = f2fp8((s * gamma[SH + dd] + beta[SH + dd]) * W8);
    }
  }
}

// ------------- QK: ker = min(relu(qk/2048 + t)^2 * 2^14, 440) fp8; single K-iter -------------
__global__ void __launch_bounds__(256)
gemm_qk(const unsigned char* __restrict__ qq,
        const unsigned char* __restrict__ kq,
        const float* __restrict__ tpl,
        unsigned char* __restrict__ ker) {
  __shared__ __align__(16) unsigned char smem8[65536];
  floatx4 acc[4][4];
  int L = blockIdx.x;
  long b = L & 7;                 // XCD-resident batch
  int w = L >> 3;                 // 0..255
  long colBase = (long)(w & 15) * 128;
  long rowBase = (long)(w >> 4) * 128;
  mfma_core_fp8(qq + b * SEQ * SH, kq + b * SEQ * SH, SH, rowBase, colBase, smem8, acc);
  unsigned char* kerb = ker + b * (long)SEQ * SEQ;
  EPILOGUE_VARS
  #pragma unroll
  for (int mi = 0; mi < 4; ++mi)
  #pragma unroll
  for (int ni = 0; ni < 4; ++ni)
  #pragma unroll
  for (int i = 0; i < 4; ++i) {
    long row = rowBase + wr + mi * 16 + fr + i;   // n
    long col = colBase + wc + ni * 16 + fc;       // m
    float val = acc[mi][ni][i] * QK_INV + tpl[row - col + 2047];
    float r = fmaxf(val, 0.0f);
    float kv = fminf(r * r * KER_SCALE, 440.0f);
    kerb[row * SEQ + col] = f2fp8(kv);
  }
}

// ------------- PV: ob = (ker @ v) * u, fp8; ob stored fp8 x64 -------------
__global__ void __launch_bounds__(256)
gemm_pv(const unsigned char* __restrict__ ker,
        const unsigned char* __restrict__ vT,
        const unsigned char* __restrict__ uq,
        unsigned char* __restrict__ obq) {
  __shared__ __align__(16) unsigned char smem8[65536];
  floatx4 acc[4][4];
  int L = blockIdx.x;
  long b = L & 7;
  int w = L >> 3;                 // 0..127
  long colBase = (long)(w & 7) * 128;   // e (fastest: ker slice reuse in L2)
  long rowBase = (long)(w >> 3) * 128;  // n
  mfma_core_fp8(ker + b * (long)SEQ * SEQ, vT + b * (long)EXP * SEQ, SEQ,
                rowBase, colBase, smem8, acc);
  const unsigned char* ub = uq + b * (long)SEQ * EXP;
  unsigned char* obb = obq + b * (long)SEQ * EXP;
  EPILOGUE_VARS
  #pragma unroll
  for (int mi = 0; mi < 4; ++mi)
  #pragma unroll
  for (int ni = 0; ni < 4; ++ni)
  #pragma unroll
  for (int i = 0; i < 4; ++i) {
    long row = rowBase + wr + mi * 16 + fr + i;
    long col = colBase + wc + ni * 16 + fc;
    float val = acc[mi][ni][i] * KER_SCALE_INV * fp82f(ub[row * EXP + col]);
    obb[row * EXP + col] = f2fp8(val);
  }
}

// ------------- OUT: out = (ob/64) @ W2 + b2 + x -------------
__global__ void __launch_bounds__(256)
gemm_out(const unsigned char* __restrict__ obq,
         const unsigned char* __restrict__ w2q,
         const float* __restrict__ b2,
         const float* __restrict__ x,
         float* __restrict__ out) {
  __shared__ __align__(16) unsigned char smem8[65536];
  floatx4 acc[4][4];
  long rowBase = (long)blockIdx.x * 128;
  long colBase = (long)blockIdx.y * 128;
  mfma_core_fp8(obq, w2q, EXP, rowBase, colBase, smem8, acc);
  EPILOGUE_VARS
  #pragma unroll
  for (int mi = 0; mi < 4; ++mi)
  #pragma unroll
  for (int ni = 0; ni < 4; ++ni)
  #pragma unroll
  for (int i = 0; i < 4; ++i) {
    long row = rowBase + wr + mi * 16 + fr + i;
    long col = colBase + wc + ni * 16 + fc;
    out[row * DIMM + col] = acc[mi][ni][i] * OUT_INV + b2[col] + x[row * DIMM + col];
  }
}

extern "C" void kernel_launch(void* const* d_in, const int* in_sizes, int n_in,
                              void* d_out, int out_size, void* d_ws, size_t ws_size,
                              hipStream_t stream) {
  const float* x          = (const float*)d_in[0];
  const float* W1         = (const float*)d_in[1];
  const float* b1         = (const float*)d_in[2];
  const float* W2         = (const float*)d_in[3];
  const float* b2         = (const float*)d_in[4];
  const float* rope_a     = (const float*)d_in[5];
  const float* rope_b     = (const float*)d_in[6];
  const float* gamma      = (const float*)d_in[7];
  const float* beta       = (const float*)d_in[8];
  const float* norm_scale = (const float*)d_in[9];
  float* out = (float*)d_out;

  char* ws = (char*)d_ws;
  size_t off = 0;
  auto nxt = [&](size_t bytes) -> void* {
    void* p = ws + off;
    off += (bytes + 255) & ~(size_t)255;
    return p;
  };
  unsigned short* xn  = (unsigned short*)nxt((size_t)ROWS * DIMM * 2);
  unsigned short* w1t = (unsigned short*)nxt((size_t)PROJ_ * DIMM * 2);
  unsigned char*  w2q = (unsigned char*)nxt((size_t)DIMM * EXP);
  unsigned char*  uq  = (unsigned char*)nxt((size_t)ROWS * EXP);
  unsigned char*  vT  = (unsigned char*)nxt((size_t)NBATCH * EXP * SEQ);
  unsigned char*  qq  = (unsigned char*)nxt((size_t)ROWS * SH);
  unsigned char*  kq  = (unsigned char*)nxt((size_t)ROWS * SH);
  float*          tpl = (float*)nxt((size_t)4096 * 4);
  unsigned char*  ker = (unsigned char*)nxt((size_t)NBATCH * SEQ * SEQ);
  unsigned char*  obq = (unsigned char*)nxt((size_t)ROWS * EXP);

  prep_kernel<<<9791, 256, 0, stream>>>(x, norm_scale, xn, W1, w1t, W2, w2q,
                                        rope_a, rope_b, tpl);
  gemm_uv<<<dim3(ROWS / 128, PROJ_ / 128), 256, 0, stream>>>(xn, w1t, b1, gamma, beta,
                                                             uq, vT, qq, kq);
  gemm_qk<<<2048, 256, 0, stream>>>(qq, kq, tpl, ker);
  gemm_pv<<<1024, 256, 0, stream>>>(ker, vT, uq, obq);
  gemm_out<<<dim3(ROWS / 128, DIMM / 128), 256, 0, stream>>>(obq, w2q, b2, x, out);
}

// Round 7
// 238.501 us; speedup vs baseline: 1.5804x; 1.5804x over previous
//
#include <hip/hip_runtime.h>
#include <math.h>

#define SEQ    2048
#define DIMM   512
#define SH     128
#define EXP    1024
#define PROJ_  2176
#define NBATCH 8
#define ROWS   16384  // NBATCH*SEQ

#define KER_SCALE     16384.0f
#define KER_SCALE_INV (1.0f / 16384.0f)
#define QK_INV        (1.0f / (4096.0f * 2048.0f))   // q,k scaled x64 each; /MAX_LEN
#define W8            64.0f                          // generic fp8 pre-scale
#define INV4096       (1.0f / 4096.0f)               // undo x64 * x64

typedef __attribute__((ext_vector_type(4))) float floatx4;
typedef __attribute__((ext_vector_type(8))) int   int8v;

__device__ __forceinline__ unsigned short f2bf(float f) {
  union { float f; unsigned int u; } v; v.f = f;
  unsigned int r = (v.u + 0x7fffu + ((v.u >> 16) & 1u)) >> 16;
  return (unsigned short)r;
}
__device__ __forceinline__ float bf2f(unsigned short h) {
  union { unsigned int u; float f; } v; v.u = ((unsigned int)h) << 16;
  return v.f;
}
__device__ __forceinline__ unsigned char f2fp8(float f) {
  return (unsigned char)(__builtin_amdgcn_cvt_pk_fp8_f32(f, 0.0f, 0, false) & 0xffu);
}
__device__ __forceinline__ float fp82f(unsigned char b) {
  int e = (b >> 3) & 15, m = b & 7;
  float v = ldexpf((float)(e ? (8 + m) : m), (e ? e : 1) - 10);
  return (b & 0x80) ? -v : v;
}

__device__ __forceinline__ void async16(const void* g, void* l) {
  __builtin_amdgcn_global_load_lds(
      (const __attribute__((address_space(1))) void*)g,
      (__attribute__((address_space(3))) void*)l, 16, 0, 0);
}

// =================== fused prep (256 threads) ===================
__device__ __forceinline__ void transpose_tile_fp8(const float* __restrict__ in,
                                                   unsigned char* __restrict__ out,
                                                   int R, int C, int bx, int by, float* tile) {
  int tx = threadIdx.x & 31, ty = threadIdx.x >> 5;
  int c0 = bx * 32, r0 = by * 32;
  #pragma unroll
  for (int j = 0; j < 32; j += 8)
    tile[(ty + j) * 33 + tx] = in[(long)(r0 + ty + j) * C + c0 + tx];
  __syncthreads();
  #pragma unroll
  for (int j = 0; j < 32; j += 8)
    out[(long)(c0 + ty + j) * R + r0 + tx] = f2fp8(tile[tx * 33 + ty + j] * W8);
}

__global__ void prep_kernel(const float* __restrict__ x, const float* __restrict__ ns,
                            unsigned char* __restrict__ xq,
                            const float* __restrict__ W1, unsigned char* __restrict__ w1q,
                            const float* __restrict__ W2, unsigned char* __restrict__ w2q,
                            const float* __restrict__ ra, const float* __restrict__ rb,
                            float* __restrict__ tpl) {
  __shared__ float sh[33 * 32];
  const int b = blockIdx.x, tid = threadIdx.x;
  if (b < 4096) {
    // ---- RMSNorm -> fp8 x64: 4 rows per block ----
    int wave = tid >> 6, lane = tid & 63;
    long row = (long)b * 4 + wave;
    const float4* xr = (const float4*)(x + row * DIMM);
    float4 v0 = xr[lane], v1 = xr[lane + 64];
    float ss = v0.x*v0.x + v0.y*v0.y + v0.z*v0.z + v0.w*v0.w
             + v1.x*v1.x + v1.y*v1.y + v1.z*v1.z + v1.w*v1.w;
    #pragma unroll
    for (int o = 32; o > 0; o >>= 1) ss += __shfl_xor(ss, o);
    float sc = rsqrtf(ss * (1.0f / DIMM) + 1e-6f) * ns[0] * W8;
    unsigned int w0 = __builtin_amdgcn_cvt_pk_fp8_f32(v0.x*sc, v0.y*sc, 0, false);
    w0 = __builtin_amdgcn_cvt_pk_fp8_f32(v0.z*sc, v0.w*sc, w0, true);
    unsigned int w1 = __builtin_amdgcn_cvt_pk_fp8_f32(v1.x*sc, v1.y*sc, 0, false);
    w1 = __builtin_amdgcn_cvt_pk_fp8_f32(v1.z*sc, v1.w*sc, w1, true);
    uint2 pk; pk.x = w0; pk.y = w1;
    ((uint2*)(xq + row * DIMM))[lane] = pk;
  } else if (b < 4096 + 4095) {
    const int d = (b - 4096) - 2047;
    float sum = 0.0f;
    for (int k = tid; k < 1024; k += 256) {
      float a1 = ra[k], a2 = ra[k + 1024];
      float b1v = rb[k], b2v = rb[k + 1024];
      float p = a1 * b1v + a2 * b2v;
      float q = a1 * b2v - a2 * b1v;
      float th = powf(10000.0f, -(float)k * (1.0f / 1024.0f));
      float ang = (float)d * th;
      sum += p * cosf(ang) + q * sinf(ang);
    }
    #pragma unroll
    for (int o = 32; o > 0; o >>= 1) sum += __shfl_xor(sum, o);
    int wave = tid >> 6, lane = tid & 63;
    if (lane == 0) sh[wave] = sum;
    __syncthreads();
    if (tid == 0) tpl[b - 4096] = sh[0] + sh[1] + sh[2] + sh[3];
  } else if (b < 9279) {
    int t = b - 8191;   // W1 (DIMM x PROJ_) -> w1q (PROJ_ x DIMM) fp8 x64
    transpose_tile_fp8(W1, w1q, DIMM, PROJ_, t % 68, t / 68, sh);
  } else {
    int t = b - 9279;   // W2 (EXP x DIMM) -> w2q (DIMM x EXP) fp8 x64
    transpose_tile_fp8(W2, w2q, EXP, DIMM, t % 16, t / 16, sh);
  }
}

// =================== single-buffer MX-fp8 MFMA core, BK=128 ===================
// C(128x128) = A . B^T ; A,B row-major fp8 e4m3, ld = K (K%128==0).
// mfma_scale 16x16x128 with unit E8M0 scales (0x7F) = 2x non-scaled fp8 rate.
// Lane quad fq owns K-block [32*fq, 32*fq+32): adjacent granule pair in the
// XOR-swizzled row (s0=(2fq)^(row&7), s0^1), read as two ds_read_b128.
__device__ __forceinline__ void mfma_core_mx(const unsigned char* __restrict__ A,
                                             const unsigned char* __restrict__ B,
                                             int K, long rowBase, long colBase,
                                             unsigned char* smem, floatx4 acc[4][4]) {
  unsigned char* As = smem;
  unsigned char* Bs = smem + 128 * 128;
  const int tid  = threadIdx.x;
  const int wave = tid >> 6;
  const int lane = tid & 63;
  const int wr   = (wave >> 1) * 64;
  const int wc   = (wave & 1) * 64;
  const int r_l  = lane >> 3;
  const int c8   = lane & 7;
  const int fm   = lane & 15;
  const int fq   = lane >> 4;

  floatx4 z = {0.0f, 0.0f, 0.0f, 0.0f};
  #pragma unroll
  for (int mi = 0; mi < 4; ++mi)
    #pragma unroll
    for (int ni = 0; ni < 4; ++ni) acc[mi][ni] = z;

  union U8 { uint4 q[2]; int8v v; };

  for (int k0 = 0; k0 < K; k0 += 128) {
    __syncthreads();
    #pragma unroll
    for (int j = 0; j < 4; ++j) {
      int row = j * 32 + wave * 8 + r_l;
      int g = c8 ^ (row & 7);
      async16(A + (rowBase + row) * (long)K + k0 + g * 16, As + (j * 32 + wave * 8) * 128);
      async16(B + (colBase + row) * (long)K + k0 + g * 16, Bs + (j * 32 + wave * 8) * 128);
    }
    __syncthreads();
    int8v av[4], bv[4];
    #pragma unroll
    for (int mi = 0; mi < 4; ++mi) {
      int row = wr + mi * 16 + fm;
      int s0 = (2 * fq) ^ (row & 7);
      U8 u;
      u.q[0] = *(const uint4*)(As + row * 128 + s0 * 16);
      u.q[1] = *(const uint4*)(As + row * 128 + (s0 ^ 1) * 16);
      av[mi] = u.v;
    }
    #pragma unroll
    for (int ni = 0; ni < 4; ++ni) {
      int row = wc + ni * 16 + fm;
      int s0 = (2 * fq) ^ (row & 7);
      U8 u;
      u.q[0] = *(const uint4*)(Bs + row * 128 + s0 * 16);
      u.q[1] = *(const uint4*)(Bs + row * 128 + (s0 ^ 1) * 16);
      bv[ni] = u.v;
    }
    #pragma unroll
    for (int mi = 0; mi < 4; ++mi)
      #pragma unroll
      for (int ni = 0; ni < 4; ++ni)
        acc[mi][ni] = __builtin_amdgcn_mfma_scale_f32_16x16x128_f8f6f4(
            av[mi], bv[ni], acc[mi][ni], 0, 0, 0, 0x7F7F7F7F, 0, 0x7F7F7F7F);
  }
}

#define EPILOGUE_VARS                                         \
  const int lane = threadIdx.x & 63, wave = threadIdx.x >> 6; \
  const int wr = (wave >> 1) * 64, wc = (wave & 1) * 64;      \
  const int fr = (lane >> 4) * 4, fc = lane & 15;

// ------------- GEMM1: t = xq@w1q/4096 + b1, swish; split u(fp8 x64), vT(fp8), q/k(fp8 x64) -------------
__global__ void __launch_bounds__(256)
gemm_uv(const unsigned char* __restrict__ xq,
        const unsigned char* __restrict__ w1q,
        const float* __restrict__ b1,
        const float* __restrict__ gamma,
        const float* __restrict__ beta,
        unsigned char* __restrict__ uq,
        unsigned char* __restrict__ vT,
        unsigned char* __restrict__ qq,
        unsigned char* __restrict__ kq) {
  __shared__ __align__(16) unsigned short smem[17408];  // 34.8 KB; core uses first 32 KB
  floatx4 acc[4][4];
  long rowBase = (long)blockIdx.x * 128;
  long colBase = (long)blockIdx.y * 128;
  mfma_core_mx(xq, w1q, DIMM, rowBase, colBase, (unsigned char*)smem, acc);
  EPILOGUE_VARS

  if (blockIdx.y < 8) {
    #pragma unroll
    for (int mi = 0; mi < 4; ++mi)
    #pragma unroll
    for (int ni = 0; ni < 4; ++ni)
    #pragma unroll
    for (int i = 0; i < 4; ++i) {
      long row = rowBase + wr + mi * 16 + fr + i;
      long col = colBase + wc + ni * 16 + fc;
      float t = acc[mi][ni][i] * INV4096 + b1[col];
      uq[row * EXP + col] = f2fp8(t / (1.0f + __expf(-t)) * W8);
    }
  } else if (blockIdx.y < 16) {
    // v region: LDS transpose -> coalesced fp8 stores into vT
    __syncthreads();
    #pragma unroll
    for (int mi = 0; mi < 4; ++mi)
    #pragma unroll
    for (int ni = 0; ni < 4; ++ni)
    #pragma unroll
    for (int i = 0; i < 4; ++i) {
      int rl = wr + mi * 16 + fr + i;     // n-local
      int cl = wc + ni * 16 + fc;         // e-local
      long col = colBase + cl;
      float t = acc[mi][ni][i] * INV4096 + b1[col];
      smem[cl * 136 + rl] = f2bf(t / (1.0f + __expf(-t)));
    }
    __syncthreads();
    long b_   = rowBase >> 11;
    long nblk = rowBase & 2047;
    long e0   = colBase - EXP;
    #pragma unroll
    for (int rep = 0; rep < 8; ++rep) {
      int cl = rep * 16 + (threadIdx.x >> 4);
      int n0 = (threadIdx.x & 15) * 8;
      const unsigned short* src = smem + cl * 136 + n0;
      unsigned int w0 = __builtin_amdgcn_cvt_pk_fp8_f32(bf2f(src[0]), bf2f(src[1]), 0, false);
      w0 = __builtin_amdgcn_cvt_pk_fp8_f32(bf2f(src[2]), bf2f(src[3]), w0, true);
      unsigned int w1 = __builtin_amdgcn_cvt_pk_fp8_f32(bf2f(src[4]), bf2f(src[5]), 0, false);
      w1 = __builtin_amdgcn_cvt_pk_fp8_f32(bf2f(src[6]), bf2f(src[7]), w1, true);
      uint2 pk; pk.x = w0; pk.y = w1;
      *(uint2*)(vT + (b_ * EXP + e0 + cl) * (long)SEQ + nblk + n0) = pk;
    }
  } else {
    #pragma unroll
    for (int mi = 0; mi < 4; ++mi)
    #pragma unroll
    for (int ni = 0; ni < 4; ++ni)
    #pragma unroll
    for (int i = 0; i < 4; ++i) {
      long row = rowBase + wr + mi * 16 + fr + i;
      long col = colBase + wc + ni * 16 + fc;
      float t = acc[mi][ni][i] * INV4096 + b1[col];
      float s = t / (1.0f + __expf(-t));
      int dd = (int)(col - 2 * EXP);
      qq[row * SH + dd] = f2fp8((s * gamma[dd] + beta[dd]) * W8);
      kq[row * SH + dd] = f2fp8((s * gamma[SH + dd] + beta[SH + dd]) * W8);
    }
  }
}

// ------------- QK: ker = min(relu(qk/2048 + t)^2 * 2^14, 440) fp8; single K-iter -------------
__global__ void __launch_bounds__(256)
gemm_qk(const unsigned char* __restrict__ qq,
        const unsigned char* __restrict__ kq,
        const float* __restrict__ tpl,
        unsigned char* __restrict__ ker) {
  __shared__ __align__(16) unsigned char smem8[32768];
  floatx4 acc[4][4];
  int L = blockIdx.x;
  long b = L & 7;                 // XCD-resident batch
  int w = L >> 3;                 // 0..255
  long colBase = (long)(w & 15) * 128;
  long rowBase = (long)(w >> 4) * 128;
  mfma_core_mx(qq + b * SEQ * SH, kq + b * SEQ * SH, SH, rowBase, colBase, smem8, acc);
  unsigned char* kerb = ker + b * (long)SEQ * SEQ;
  EPILOGUE_VARS
  #pragma unroll
  for (int mi = 0; mi < 4; ++mi)
  #pragma unroll
  for (int ni = 0; ni < 4; ++ni)
  #pragma unroll
  for (int i = 0; i < 4; ++i) {
    long row = rowBase + wr + mi * 16 + fr + i;   // n
    long col = colBase + wc + ni * 16 + fc;       // m
    float val = acc[mi][ni][i] * QK_INV + tpl[row - col + 2047];
    float r = fmaxf(val, 0.0f);
    float kv = fminf(r * r * KER_SCALE, 440.0f);
    kerb[row * SEQ + col] = f2fp8(kv);
  }
}

// ------------- PV: ob = (ker @ v) * u; ob stored fp8 x64 -------------
__global__ void __launch_bounds__(256)
gemm_pv(const unsigned char* __restrict__ ker,
        const unsigned char* __restrict__ vT,
        const unsigned char* __restrict__ uq,
        unsigned char* __restrict__ obq) {
  __shared__ __align__(16) unsigned char smem8[32768];
  floatx4 acc[4][4];
  int L = blockIdx.x;
  long b = L & 7;
  int w = L >> 3;                 // 0..127
  long colBase = (long)(w & 7) * 128;   // e (fastest: ker slice reuse in L2)
  long rowBase = (long)(w >> 3) * 128;  // n
  mfma_core_mx(ker + b * (long)SEQ * SEQ, vT + b * (long)EXP * SEQ, SEQ,
               rowBase, colBase, smem8, acc);
  const unsigned char* ub = uq + b * (long)SEQ * EXP;
  unsigned char* obb = obq + b * (long)SEQ * EXP;
  EPILOGUE_VARS
  #pragma unroll
  for (int mi = 0; mi < 4; ++mi)
  #pragma unroll
  for (int ni = 0; ni < 4; ++ni)
  #pragma unroll
  for (int i = 0; i < 4; ++i) {
    long row = rowBase + wr + mi * 16 + fr + i;
    long col = colBase + wc + ni * 16 + fc;
    float val = acc[mi][ni][i] * KER_SCALE_INV * fp82f(ub[row * EXP + col]);
    obb[row * EXP + col] = f2fp8(val);
  }
}

// ------------- OUT: out = (ob/64) @ (W2) + b2 + x -------------
__global__ void __launch_bounds__(256)
gemm_out(const unsigned char* __restrict__ obq,
         const unsigned char* __restrict__ w2q,
         const float* __restrict__ b2,
         const float* __restrict__ x,
         float* __restrict__ out) {
  __shared__ __align__(16) unsigned char smem8[32768];
  floatx4 acc[4][4];
  long rowBase = (long)blockIdx.x * 128;
  long colBase = (long)blockIdx.y * 128;
  mfma_core_mx(obq, w2q, EXP, rowBase, colBase, smem8, acc);
  EPILOGUE_VARS
  #pragma unroll
  for (int mi = 0; mi < 4; ++mi)
  #pragma unroll
  for (int ni = 0; ni < 4; ++ni)
  #pragma unroll
  for (int i = 0; i < 4; ++i) {
    long row = rowBase + wr + mi * 16 + fr + i;
    long col = colBase + wc + ni * 16 + fc;
    out[row * DIMM + col] = acc[mi][ni][i] * INV4096 + b2[col] + x[row * DIMM + col];
  }
}

extern "C" void kernel_launch(void* const* d_in, const int* in_sizes, int n_in,
                              void* d_out, int out_size, void* d_ws, size_t ws_size,
                              hipStream_t stream) {
  const float* x          = (const float*)d_in[0];
  const float* W1         = (const float*)d_in[1];
  const float* b1         = (const float*)d_in[2];
  const float* W2         = (const float*)d_in[3];
  const float* b2         = (const float*)d_in[4];
  const float* rope_a     = (const float*)d_in[5];
  const float* rope_b     = (const float*)d_in[6];
  const float* gamma      = (const float*)d_in[7];
  const float* beta       = (const float*)d_in[8];
  const float* norm_scale = (const float*)d_in[9];
  float* out = (float*)d_out;

  char* ws = (char*)d_ws;
  size_t off = 0;
  auto nxt = [&](size_t bytes) -> void* {
    void* p = ws + off;
    off += (bytes + 255) & ~(size_t)255;
    return p;
  };
  unsigned char*  xq  = (unsigned char*)nxt((size_t)ROWS * DIMM);
  unsigned char*  w1q = (unsigned char*)nxt((size_t)PROJ_ * DIMM);
  unsigned char*  w2q = (unsigned char*)nxt((size_t)DIMM * EXP);
  unsigned char*  uq  = (unsigned char*)nxt((size_t)ROWS * EXP);
  unsigned char*  vT  = (unsigned char*)nxt((size_t)NBATCH * EXP * SEQ);
  unsigned char*  qq  = (unsigned char*)nxt((size_t)ROWS * SH);
  unsigned char*  kq  = (unsigned char*)nxt((size_t)ROWS * SH);
  float*          tpl = (float*)nxt((size_t)4096 * 4);
  unsigned char*  ker = (unsigned char*)nxt((size_t)NBATCH * SEQ * SEQ);
  unsigned char*  obq = (unsigned char*)nxt((size_t)ROWS * EXP);

  prep_kernel<<<9791, 256, 0, stream>>>(x, norm_scale, xq, W1, w1q, W2, w2q,
                                        rope_a, rope_b, tpl);
  gemm_uv<<<dim3(ROWS / 128, PROJ_ / 128), 256, 0, stream>>>(xq, w1q, b1, gamma, beta,
                                                             uq, vT, qq, kq);
  gemm_qk<<<2048, 256, 0, stream>>>(qq, kq, tpl, ker);
  gemm_pv<<<1024, 256, 0, stream>>>(ker, vT, uq, obq);
  gemm_out<<<dim3(ROWS / 128, DIMM / 128), 256, 0, stream>>>(obq, w2q, b2, x, out);
}

// Round 8
// 226.564 us; speedup vs baseline: 1.6637x; 1.0527x over previous
//
#include <hip/hip_runtime.h>
#include <math.h>

#define SEQ    2048
#define DIMM   512
#define SH     128
#define EXP    1024
#define PROJ_  2176
#define NBATCH 8
#define ROWS   16384  // NBATCH*SEQ

#define KER_SCALE     16384.0f
#define KER_SCALE_INV (1.0f / 16384.0f)
#define QK_INV        (1.0f / (4096.0f * 2048.0f))   // q,k scaled x64 each; /MAX_LEN
#define W8            64.0f                          // generic fp8 pre-scale
#define INV4096       (1.0f / 4096.0f)               // undo x64 * x64

typedef __attribute__((ext_vector_type(4))) float floatx4;
typedef __attribute__((ext_vector_type(8))) int   int8v;

__device__ __forceinline__ unsigned short f2bf(float f) {
  union { float f; unsigned int u; } v; v.f = f;
  unsigned int r = (v.u + 0x7fffu + ((v.u >> 16) & 1u)) >> 16;
  return (unsigned short)r;
}
__device__ __forceinline__ float bf2f(unsigned short h) {
  union { unsigned int u; float f; } v; v.u = ((unsigned int)h) << 16;
  return v.f;
}
__device__ __forceinline__ unsigned char f2fp8(float f) {
  return (unsigned char)(__builtin_amdgcn_cvt_pk_fp8_f32(f, 0.0f, 0, false) & 0xffu);
}
__device__ __forceinline__ unsigned int pk4fp8(float a, float b, float c, float d) {
  unsigned int w = __builtin_amdgcn_cvt_pk_fp8_f32(a, b, 0, false);
  return __builtin_amdgcn_cvt_pk_fp8_f32(c, d, w, true);
}
__device__ __forceinline__ float fp82f(unsigned char b) {
  int e = (b >> 3) & 15, m = b & 7;
  float v = ldexpf((float)(e ? (8 + m) : m), (e ? e : 1) - 10);
  return (b & 0x80) ? -v : v;
}

__device__ __forceinline__ void async16(const void* g, void* l) {
  __builtin_amdgcn_global_load_lds(
      (const __attribute__((address_space(1))) void*)g,
      (__attribute__((address_space(3))) void*)l, 16, 0, 0);
}

// =================== fused prep (256 threads) ===================
__device__ __forceinline__ void transpose_tile_fp8(const float* __restrict__ in,
                                                   unsigned char* __restrict__ out,
                                                   int R, int C, int bx, int by, float* tile) {
  int tx = threadIdx.x & 31, ty = threadIdx.x >> 5;
  int c0 = bx * 32, r0 = by * 32;
  #pragma unroll
  for (int j = 0; j < 32; j += 8)
    tile[(ty + j) * 33 + tx] = in[(long)(r0 + ty + j) * C + c0 + tx];
  __syncthreads();
  #pragma unroll
  for (int j = 0; j < 32; j += 8)
    out[(long)(c0 + ty + j) * R + r0 + tx] = f2fp8(tile[tx * 33 + ty + j] * W8);
}

__global__ void prep_kernel(const float* __restrict__ x, const float* __restrict__ ns,
                            unsigned char* __restrict__ xq,
                            const float* __restrict__ W1, unsigned char* __restrict__ w1q,
                            const float* __restrict__ W2, unsigned char* __restrict__ w2q,
                            const float* __restrict__ ra, const float* __restrict__ rb,
                            float* __restrict__ tpl) {
  __shared__ float sh[33 * 32];
  const int b = blockIdx.x, tid = threadIdx.x;
  if (b < 4096) {
    // ---- RMSNorm -> fp8 x64: 4 rows per block ----
    int wave = tid >> 6, lane = tid & 63;
    long row = (long)b * 4 + wave;
    const float4* xr = (const float4*)(x + row * DIMM);
    float4 v0 = xr[lane], v1 = xr[lane + 64];
    float ss = v0.x*v0.x + v0.y*v0.y + v0.z*v0.z + v0.w*v0.w
             + v1.x*v1.x + v1.y*v1.y + v1.z*v1.z + v1.w*v1.w;
    #pragma unroll
    for (int o = 32; o > 0; o >>= 1) ss += __shfl_xor(ss, o);
    float sc = rsqrtf(ss * (1.0f / DIMM) + 1e-6f) * ns[0] * W8;
    uint2 pk;
    pk.x = pk4fp8(v0.x*sc, v0.y*sc, v0.z*sc, v0.w*sc);
    pk.y = pk4fp8(v1.x*sc, v1.y*sc, v1.z*sc, v1.w*sc);
    ((uint2*)(xq + row * DIMM))[lane] = pk;
  } else if (b < 4096 + 4095) {
    const int d = (b - 4096) - 2047;
    float sum = 0.0f;
    for (int k = tid; k < 1024; k += 256) {
      float a1 = ra[k], a2 = ra[k + 1024];
      float b1v = rb[k], b2v = rb[k + 1024];
      float p = a1 * b1v + a2 * b2v;
      float q = a1 * b2v - a2 * b1v;
      float th = exp2f((float)k * (-13.287712379549449f / 1024.0f));
      float ang = (float)d * th;
      sum += p * cosf(ang) + q * sinf(ang);
    }
    #pragma unroll
    for (int o = 32; o > 0; o >>= 1) sum += __shfl_xor(sum, o);
    int wave = tid >> 6, lane = tid & 63;
    if (lane == 0) sh[wave] = sum;
    __syncthreads();
    if (tid == 0) tpl[b - 4096] = sh[0] + sh[1] + sh[2] + sh[3];
  } else if (b < 9279) {
    int t = b - 8191;   // W1 (DIMM x PROJ_) -> w1q (PROJ_ x DIMM) fp8 x64
    transpose_tile_fp8(W1, w1q, DIMM, PROJ_, t % 68, t / 68, sh);
  } else {
    int t = b - 9279;   // W2 (EXP x DIMM) -> w2q (DIMM x EXP) fp8 x64
    transpose_tile_fp8(W2, w2q, EXP, DIMM, t % 16, t / 16, sh);
  }
}

// =================== single-buffer MX-fp8 MFMA core, BK=128 ===================
// C(128x128) = A . B^T ; A,B row-major fp8 e4m3, ld = K (K%128==0).
__device__ __forceinline__ void mfma_core_mx(const unsigned char* __restrict__ A,
                                             const unsigned char* __restrict__ B,
                                             int K, long rowBase, long colBase,
                                             unsigned char* smem, floatx4 acc[4][4]) {
  unsigned char* As = smem;
  unsigned char* Bs = smem + 128 * 128;
  const int tid  = threadIdx.x;
  const int wave = tid >> 6;
  const int lane = tid & 63;
  const int wr   = (wave >> 1) * 64;
  const int wc   = (wave & 1) * 64;
  const int r_l  = lane >> 3;
  const int c8   = lane & 7;
  const int fm   = lane & 15;
  const int fq   = lane >> 4;

  floatx4 z = {0.0f, 0.0f, 0.0f, 0.0f};
  #pragma unroll
  for (int mi = 0; mi < 4; ++mi)
    #pragma unroll
    for (int ni = 0; ni < 4; ++ni) acc[mi][ni] = z;

  union U8 { uint4 q[2]; int8v v; };

  for (int k0 = 0; k0 < K; k0 += 128) {
    __syncthreads();
    #pragma unroll
    for (int j = 0; j < 4; ++j) {
      int row = j * 32 + wave * 8 + r_l;
      int g = c8 ^ (row & 7);
      async16(A + (rowBase + row) * (long)K + k0 + g * 16, As + (j * 32 + wave * 8) * 128);
      async16(B + (colBase + row) * (long)K + k0 + g * 16, Bs + (j * 32 + wave * 8) * 128);
    }
    __syncthreads();
    int8v av[4], bv[4];
    #pragma unroll
    for (int mi = 0; mi < 4; ++mi) {
      int row = wr + mi * 16 + fm;
      int s0 = (2 * fq) ^ (row & 7);
      U8 u;
      u.q[0] = *(const uint4*)(As + row * 128 + s0 * 16);
      u.q[1] = *(const uint4*)(As + row * 128 + (s0 ^ 1) * 16);
      av[mi] = u.v;
    }
    #pragma unroll
    for (int ni = 0; ni < 4; ++ni) {
      int row = wc + ni * 16 + fm;
      int s0 = (2 * fq) ^ (row & 7);
      U8 u;
      u.q[0] = *(const uint4*)(Bs + row * 128 + s0 * 16);
      u.q[1] = *(const uint4*)(Bs + row * 128 + (s0 ^ 1) * 16);
      bv[ni] = u.v;
    }
    #pragma unroll
    for (int mi = 0; mi < 4; ++mi)
      #pragma unroll
      for (int ni = 0; ni < 4; ++ni)
        acc[mi][ni] = __builtin_amdgcn_mfma_scale_f32_16x16x128_f8f6f4(
            av[mi], bv[ni], acc[mi][ni], 0, 0, 0, 0x7F7F7F7F, 0, 0x7F7F7F7F);
  }
}

#define EPILOGUE_VARS                                         \
  const int lane = threadIdx.x & 63, wave = threadIdx.x >> 6; \
  const int wr = (wave >> 1) * 64, wc = (wave & 1) * 64;      \
  const int fr = (lane >> 4) * 4, fc = lane & 15;

// ------------- GEMM1 (unchanged orientation): split u(fp8 x64), vT(fp8), q/k(fp8 x64) -------------
__global__ void __launch_bounds__(256)
gemm_uv(const unsigned char* __restrict__ xq,
        const unsigned char* __restrict__ w1q,
        const float* __restrict__ b1,
        const float* __restrict__ gamma,
        const float* __restrict__ beta,
        unsigned char* __restrict__ uq,
        unsigned char* __restrict__ vT,
        unsigned char* __restrict__ qq,
        unsigned char* __restrict__ kq) {
  __shared__ __align__(16) unsigned short smem[17408];  // core uses first 32 KB
  floatx4 acc[4][4];
  long rowBase = (long)blockIdx.x * 128;
  long colBase = (long)blockIdx.y * 128;
  mfma_core_mx(xq, w1q, DIMM, rowBase, colBase, (unsigned char*)smem, acc);
  EPILOGUE_VARS

  if (blockIdx.y < 8) {
    #pragma unroll
    for (int mi = 0; mi < 4; ++mi)
    #pragma unroll
    for (int ni = 0; ni < 4; ++ni)
    #pragma unroll
    for (int i = 0; i < 4; ++i) {
      long row = rowBase + wr + mi * 16 + fr + i;
      long col = colBase + wc + ni * 16 + fc;
      float t = acc[mi][ni][i] * INV4096 + b1[col];
      uq[row * EXP + col] = f2fp8(t / (1.0f + __expf(-t)) * W8);
    }
  } else if (blockIdx.y < 16) {
    // v region: LDS transpose -> coalesced fp8 stores into vT
    __syncthreads();
    #pragma unroll
    for (int mi = 0; mi < 4; ++mi)
    #pragma unroll
    for (int ni = 0; ni < 4; ++ni)
    #pragma unroll
    for (int i = 0; i < 4; ++i) {
      int rl = wr + mi * 16 + fr + i;     // n-local
      int cl = wc + ni * 16 + fc;         // e-local
      long col = colBase + cl;
      float t = acc[mi][ni][i] * INV4096 + b1[col];
      smem[cl * 136 + rl] = f2bf(t / (1.0f + __expf(-t)));
    }
    __syncthreads();
    long b_   = rowBase >> 11;
    long nblk = rowBase & 2047;
    long e0   = colBase - EXP;
    #pragma unroll
    for (int rep = 0; rep < 8; ++rep) {
      int cl = rep * 16 + (threadIdx.x >> 4);
      int n0 = (threadIdx.x & 15) * 8;
      const unsigned short* src = smem + cl * 136 + n0;
      uint2 pk;
      pk.x = pk4fp8(bf2f(src[0]), bf2f(src[1]), bf2f(src[2]), bf2f(src[3]));
      pk.y = pk4fp8(bf2f(src[4]), bf2f(src[5]), bf2f(src[6]), bf2f(src[7]));
      *(uint2*)(vT + (b_ * EXP + e0 + cl) * (long)SEQ + nblk + n0) = pk;
    }
  } else {
    #pragma unroll
    for (int mi = 0; mi < 4; ++mi)
    #pragma unroll
    for (int ni = 0; ni < 4; ++ni)
    #pragma unroll
    for (int i = 0; i < 4; ++i) {
      long row = rowBase + wr + mi * 16 + fr + i;
      long col = colBase + wc + ni * 16 + fc;
      float t = acc[mi][ni][i] * INV4096 + b1[col];
      float s = t / (1.0f + __expf(-t));
      int dd = (int)(col - 2 * EXP);
      qq[row * SH + dd] = f2fp8((s * gamma[dd] + beta[dd]) * W8);
      kq[row * SH + dd] = f2fp8((s * gamma[SH + dd] + beta[SH + dd]) * W8);
    }
  }
}

// ------------- QK (swapped: A=k rows m, B=q rows n -> C=S^T[m][n]) -------------
// ker[n][m] = fp8(min(relu(acc*QK_INV + tpl[n-m])^2 * 2^14, 440)); coalesced row stores.
__global__ void __launch_bounds__(256)
gemm_qk(const unsigned char* __restrict__ kq,
        const unsigned char* __restrict__ qq,
        const float* __restrict__ tpl,
        unsigned char* __restrict__ ker) {
  __shared__ __align__(16) unsigned char smem8[32768];
  floatx4 acc[4][4];
  int L = blockIdx.x;
  long b = L & 7;                 // XCD-resident batch
  int w = L >> 3;                 // 0..255
  long mBase = (long)(w & 15) * 128;
  long nBase = (long)(w >> 4) * 128;
  mfma_core_mx(kq + b * SEQ * SH, qq + b * SEQ * SH, SH, mBase, nBase, smem8, acc);
  unsigned char* kerb = ker + b * (long)SEQ * SEQ;
  EPILOGUE_VARS
  (void)fr;
  __syncthreads();  // all waves done with staged tiles; reuse smem8 as [n][m] tile
  #pragma unroll
  for (int mi = 0; mi < 4; ++mi)
  #pragma unroll
  for (int ni = 0; ni < 4; ++ni) {
    int m_loc0 = wr + mi * 16 + (lane >> 4) * 4;   // 4-run along m (A-rows)
    int n_loc  = wc + ni * 16 + fc;
    long n = nBase + n_loc;
    long m0 = mBase + m_loc0;
    float v[4];
    #pragma unroll
    for (int i = 0; i < 4; ++i) {
      float val = acc[mi][ni][i] * QK_INV + tpl[n - (m0 + i) + 2047];
      float r = fmaxf(val, 0.0f);
      v[i] = fminf(r * r * KER_SCALE, 440.0f);
    }
    *(unsigned int*)(smem8 + n_loc * 136 + m_loc0) = pk4fp8(v[0], v[1], v[2], v[3]);
  }
  __syncthreads();
  #pragma unroll
  for (int rep = 0; rep < 4; ++rep) {
    int n_loc = rep * 32 + (threadIdx.x >> 3);
    int m_seg = (threadIdx.x & 7) * 16;
    uint4 v16 = *(const uint4*)(smem8 + n_loc * 136 + m_seg);
    *(uint4*)(kerb + (nBase + n_loc) * (long)SEQ + mBase + m_seg) = v16;
  }
}

// ------------- PV (swapped: A=vT rows e, B=ker rows n -> C[e][n]) -------------
// obq[n][e] = fp8(acc * 2^-14 * u*64); u fused at pack; coalesced row stores.
__global__ void __launch_bounds__(256)
gemm_pv(const unsigned char* __restrict__ ker,
        const unsigned char* __restrict__ vT,
        const unsigned char* __restrict__ uq,
        unsigned char* __restrict__ obq) {
  __shared__ __align__(16) unsigned char smem8[32768];
  floatx4 acc[4][4];
  int L = blockIdx.x;
  long b = L & 7;
  int w = L >> 3;                 // 0..127
  long eBase = (long)(w & 7) * 128;    // e fastest: ker n-slice reuse in L2
  long nBase = (long)(w >> 3) * 128;
  mfma_core_mx(vT + b * (long)EXP * SEQ, ker + b * (long)SEQ * SEQ, SEQ,
               eBase, nBase, smem8, acc);
  const unsigned char* ub = uq + b * (long)SEQ * EXP;
  unsigned char* obb = obq + b * (long)SEQ * EXP;
  EPILOGUE_VARS
  (void)fr;
  __syncthreads();  // reuse smem8 as [n][e] tile
  #pragma unroll
  for (int mi = 0; mi < 4; ++mi)
  #pragma unroll
  for (int ni = 0; ni < 4; ++ni) {
    int e_loc0 = wr + mi * 16 + (lane >> 4) * 4;   // 4-run along e (A-rows)
    int n_loc  = wc + ni * 16 + fc;
    unsigned int uw = *(const unsigned int*)(ub + (nBase + n_loc) * (long)EXP + eBase + e_loc0);
    float v[4];
    #pragma unroll
    for (int i = 0; i < 4; ++i) {
      float u = fp82f((unsigned char)(uw >> (8 * i)));
      v[i] = acc[mi][ni][i] * KER_SCALE_INV * u;
    }
    *(unsigned int*)(smem8 + n_loc * 136 + e_loc0) = pk4fp8(v[0], v[1], v[2], v[3]);
  }
  __syncthreads();
  #pragma unroll
  for (int rep = 0; rep < 4; ++rep) {
    int n_loc = rep * 32 + (threadIdx.x >> 3);
    int e_seg = (threadIdx.x & 7) * 16;
    uint4 v16 = *(const uint4*)(smem8 + n_loc * 136 + e_seg);
    *(uint4*)(obb + (nBase + n_loc) * (long)EXP + eBase + e_seg) = v16;
  }
}

// ------------- OUT: out = (obq/64) @ (W2) + b2 + x (unchanged) -------------
__global__ void __launch_bounds__(256)
gemm_out(const unsigned char* __restrict__ obq,
         const unsigned char* __restrict__ w2q,
         const float* __restrict__ b2,
         const float* __restrict__ x,
         float* __restrict__ out) {
  __shared__ __align__(16) unsigned char smem8[32768];
  floatx4 acc[4][4];
  long rowBase = (long)blockIdx.x * 128;
  long colBase = (long)blockIdx.y * 128;
  mfma_core_mx(obq, w2q, EXP, rowBase, colBase, smem8, acc);
  EPILOGUE_VARS
  #pragma unroll
  for (int mi = 0; mi < 4; ++mi)
  #pragma unroll
  for (int ni = 0; ni < 4; ++ni)
  #pragma unroll
  for (int i = 0; i < 4; ++i) {
    long row = rowBase + wr + mi * 16 + fr + i;
    long col = colBase + wc + ni * 16 + fc;
    out[row * DIMM + col] = acc[mi][ni][i] * INV4096 + b2[col] + x[row * DIMM + col];
  }
}

extern "C" void kernel_launch(void* const* d_in, const int* in_sizes, int n_in,
                              void* d_out, int out_size, void* d_ws, size_t ws_size,
                              hipStream_t stream) {
  const float* x          = (const float*)d_in[0];
  const float* W1         = (const float*)d_in[1];
  const float* b1         = (const float*)d_in[2];
  const float* W2         = (const float*)d_in[3];
  const float* b2         = (const float*)d_in[4];
  const float* rope_a     = (const float*)d_in[5];
  const float* rope_b     = (const float*)d_in[6];
  const float* gamma      = (const float*)d_in[7];
  const float* beta       = (const float*)d_in[8];
  const float* norm_scale = (const float*)d_in[9];
  float* out = (float*)d_out;

  char* ws = (char*)d_ws;
  size_t off = 0;
  auto nxt = [&](size_t bytes) -> void* {
    void* p = ws + off;
    off += (bytes + 255) & ~(size_t)255;
    return p;
  };
  unsigned char*  xq  = (unsigned char*)nxt((size_t)ROWS * DIMM);
  unsigned char*  w1q = (unsigned char*)nxt((size_t)PROJ_ * DIMM);
  unsigned char*  w2q = (unsigned char*)nxt((size_t)DIMM * EXP);
  unsigned char*  uq  = (unsigned char*)nxt((size_t)ROWS * EXP);
  unsigned char*  vT  = (unsigned char*)nxt((size_t)NBATCH * EXP * SEQ);
  unsigned char*  qq  = (unsigned char*)nxt((size_t)ROWS * SH);
  unsigned char*  kq  = (unsigned char*)nxt((size_t)ROWS * SH);
  float*          tpl = (float*)nxt((size_t)4096 * 4);
  unsigned char*  ker = (unsigned char*)nxt((size_t)NBATCH * SEQ * SEQ);
  unsigned char*  obq = (unsigned char*)nxt((size_t)ROWS * EXP);

  prep_kernel<<<9791, 256, 0, stream>>>(x, norm_scale, xq, W1, w1q, W2, w2q,
                                        rope_a, rope_b, tpl);
  gemm_uv<<<dim3(ROWS / 128, PROJ_ / 128), 256, 0, stream>>>(xq, w1q, b1, gamma, beta,
                                                             uq, vT, qq, kq);
  gemm_qk<<<2048, 256, 0, stream>>>(kq, qq, tpl, ker);
  gemm_pv<<<1024, 256, 0, stream>>>(ker, vT, uq, obq);
  gemm_out<<<dim3(ROWS / 128, DIMM / 128), 256, 0, stream>>>(obq, w2q, b2, x, out);
}